// Round 6
// baseline (707.004 us; speedup 1.0000x reference)
//
#include <hip/hip_runtime.h>
#include <math.h>

#define N_NODES 50000
#define N_EDGES 800000
#define IN_CH 128
#define HC 256      // HEADS * OUT_C
#define OUT_CC 64
#define HEADS 4
#define NEG_SLOPE 0.2f

static __device__ __forceinline__ float leaky(float v) {
  return v > 0.f ? v : NEG_SLOPE * v;
}

// ---------------- GEMM: C[M,Nc] = A[M,K] @ B[K,Nc] (+bias) ----------------
// 64x64 tile, 256 threads (16x16), 4x4 micro-tile per thread, BK=64.
__global__ __launch_bounds__(256) void gemm_kernel(
    const float* __restrict__ A, const float* __restrict__ B,
    const float* __restrict__ bias, float* __restrict__ C,
    int M, int K, int Nc) {
  __shared__ float As[64][68];
  __shared__ float Bs[64][68];
  const int bm = blockIdx.x * 64, bn = blockIdx.y * 64;
  const int tid = threadIdx.x;
  const int tr = tid >> 4, tc = tid & 15;
  float acc[4][4] = {};
  for (int k0 = 0; k0 < K; k0 += 64) {
    // stage A tile (64 rows x 64 k) and B tile (64 k x 64 cols)
    for (int i = tid; i < 64 * 16; i += 256) {
      int r = i >> 4, c4 = (i & 15) << 2;
      int gr = bm + r;
      float4 v = make_float4(0.f, 0.f, 0.f, 0.f);
      if (gr < M) v = *(const float4*)(A + (size_t)gr * K + k0 + c4);
      *(float4*)&As[r][c4] = v;
      int gk = k0 + r;
      float4 w = *(const float4*)(B + (size_t)gk * Nc + bn + c4);
      *(float4*)&Bs[r][c4] = w;
    }
    __syncthreads();
    #pragma unroll 16
    for (int kk = 0; kk < 64; ++kk) {
      float a0 = As[tr * 4 + 0][kk];
      float a1 = As[tr * 4 + 1][kk];
      float a2 = As[tr * 4 + 2][kk];
      float a3 = As[tr * 4 + 3][kk];
      float4 b = *(float4*)&Bs[kk][tc * 4];
      acc[0][0] += a0 * b.x; acc[0][1] += a0 * b.y; acc[0][2] += a0 * b.z; acc[0][3] += a0 * b.w;
      acc[1][0] += a1 * b.x; acc[1][1] += a1 * b.y; acc[1][2] += a1 * b.z; acc[1][3] += a1 * b.w;
      acc[2][0] += a2 * b.x; acc[2][1] += a2 * b.y; acc[2][2] += a2 * b.z; acc[2][3] += a2 * b.w;
      acc[3][0] += a3 * b.x; acc[3][1] += a3 * b.y; acc[3][2] += a3 * b.z; acc[3][3] += a3 * b.w;
    }
    __syncthreads();
  }
  float4 bv = make_float4(0.f, 0.f, 0.f, 0.f);
  if (bias) bv = *(const float4*)(bias + bn + tc * 4);
  #pragma unroll
  for (int i = 0; i < 4; ++i) {
    int gr = bm + tr * 4 + i;
    if (gr >= M) continue;
    float4 o = make_float4(acc[i][0] + bv.x, acc[i][1] + bv.y,
                           acc[i][2] + bv.z, acc[i][3] + bv.w);
    *(float4*)(C + (size_t)gr * Nc + bn + tc * 4) = o;
  }
}

// ---------------- per-node attention logits: al[n,h] = <h[n,h,:], a[h,:]> ----------------
__global__ __launch_bounds__(256) void al_kernel(
    const float* __restrict__ hbuf, const float* __restrict__ a_src,
    const float* __restrict__ a_dst, float* __restrict__ al_s,
    float* __restrict__ al_d, int n) {
  int node = blockIdx.x * 4 + (threadIdx.x >> 6);
  int lane = threadIdx.x & 63;
  if (node >= n) return;
  const float* row = hbuf + (size_t)node * HC;
  float s[HEADS], d[HEADS];
  #pragma unroll
  for (int hh = 0; hh < HEADS; ++hh) {
    float v = row[hh * 64 + lane];
    s[hh] = v * a_src[hh * 64 + lane];
    d[hh] = v * a_dst[hh * 64 + lane];
  }
  #pragma unroll
  for (int o = 32; o; o >>= 1) {
    #pragma unroll
    for (int hh = 0; hh < HEADS; ++hh) {
      s[hh] += __shfl_down(s[hh], o);
      d[hh] += __shfl_down(d[hh], o);
    }
  }
  if (lane == 0) {
    *(float4*)(al_s + (size_t)node * 4) = make_float4(s[0], s[1], s[2], s[3]);
    *(float4*)(al_d + (size_t)node * 4) = make_float4(d[0], d[1], d[2], d[3]);
  }
}

// ---------------- CSR build ----------------
__global__ void init_counts(int* __restrict__ cnt, int n) {
  int i = blockIdx.x * blockDim.x + threadIdx.x;
  if (i < n) cnt[i] = 1;  // self loop
}

__global__ void count_dst(const int* __restrict__ dst, int E, int* __restrict__ cnt) {
  int i = blockIdx.x * blockDim.x + threadIdx.x;
  if (i < E) atomicAdd(&cnt[dst[i]], 1);
}

// per-block exclusive scan over 1024-element chunks
__global__ __launch_bounds__(256) void scan_blocks(
    const int* __restrict__ cnt, int* __restrict__ excl,
    int* __restrict__ bsums, int n) {
  __shared__ int ts[256];
  int b = blockIdx.x, tid = threadIdx.x;
  int base = b * 1024 + tid * 4;
  int v[4]; int run = 0;
  #pragma unroll
  for (int j = 0; j < 4; ++j) {
    v[j] = (base + j < n) ? cnt[base + j] : 0;
    run += v[j];
  }
  ts[tid] = run;
  __syncthreads();
  for (int o = 1; o < 256; o <<= 1) {
    int t = (tid >= o) ? ts[tid - o] : 0;
    __syncthreads();
    ts[tid] += t;
    __syncthreads();
  }
  int acc = ts[tid] - run;
  #pragma unroll
  for (int j = 0; j < 4; ++j) {
    if (base + j < n) excl[base + j] = acc;
    acc += v[j];
  }
  if (tid == 255) bsums[b] = ts[255];
}

__global__ void scan_bsums(int* __restrict__ bsums, int nb) {
  if (threadIdx.x == 0 && blockIdx.x == 0) {
    int a = 0;
    for (int i = 0; i < nb; ++i) { int t = bsums[i]; bsums[i] = a; a += t; }
  }
}

__global__ void add_back(int* __restrict__ row_ptr, const int* __restrict__ bsums,
                         int* __restrict__ wp, int n, int total) {
  int i = blockIdx.x * blockDim.x + threadIdx.x;
  if (i < n) {
    int v = row_ptr[i] + bsums[i >> 10];
    row_ptr[i] = v;
    wp[i] = v;
  }
  if (i == n) row_ptr[n] = total;
}

__global__ void scatter_edges(const int* __restrict__ src, const int* __restrict__ dst,
                              int E, int n, int* __restrict__ wp, int* __restrict__ csr) {
  int i = blockIdx.x * blockDim.x + threadIdx.x;
  if (i < E) {
    int p = atomicAdd(&wp[dst[i]], 1);
    csr[p] = src[i];
  } else if (i < E + n) {
    int node = i - E;
    int p = atomicAdd(&wp[node], 1);
    csr[p] = node;
  }
}

// ---------------- GAT aggregation: one wave per dst node, online softmax ----------------
template <bool MEAN>
__global__ __launch_bounds__(256) void agg_kernel(
    const float* __restrict__ hbuf, const float* __restrict__ al_s,
    const float* __restrict__ al_d, const int* __restrict__ row_ptr,
    const int* __restrict__ csr_src, const float* __restrict__ bias,
    const float* __restrict__ extra, float* __restrict__ outp, int n) {
  int node = blockIdx.x * 4 + (threadIdx.x >> 6);
  int lane = threadIdx.x & 63;
  if (node >= n) return;
  int beg = row_ptr[node], end = row_ptr[node + 1];
  float4 ald4 = *(const float4*)(al_d + (size_t)node * 4);
  float ald[4] = {ald4.x, ald4.y, ald4.z, ald4.w};
  float m[4] = {-INFINITY, -INFINITY, -INFINITY, -INFINITY};
  float s[4] = {0.f, 0.f, 0.f, 0.f};
  float acc[4] = {0.f, 0.f, 0.f, 0.f};
  for (int i = beg; i < end; ++i) {
    int src = csr_src[i];
    float4 als4 = *(const float4*)(al_s + (size_t)src * 4);
    const float* hr = hbuf + (size_t)src * HC;
    float e[4] = {leaky(als4.x + ald[0]), leaky(als4.y + ald[1]),
                  leaky(als4.z + ald[2]), leaky(als4.w + ald[3])};
    #pragma unroll
    for (int hh = 0; hh < 4; ++hh) {
      float mn = fmaxf(m[hh], e[hh]);
      float sc = __expf(m[hh] - mn);
      float p  = __expf(e[hh] - mn);
      float hv = hr[hh * 64 + lane];
      s[hh] = s[hh] * sc + p;
      acc[hh] = acc[hh] * sc + p * hv;
      m[hh] = mn;
    }
  }
  if (!MEAN) {
    #pragma unroll
    for (int hh = 0; hh < 4; ++hh)
      outp[(size_t)node * HC + hh * 64 + lane] =
          acc[hh] / (s[hh] + 1e-16f) + bias[hh * 64 + lane];
  } else {
    float r = 0.f;
    #pragma unroll
    for (int hh = 0; hh < 4; ++hh) r += acc[hh] / (s[hh] + 1e-16f);
    r *= 0.25f;
    outp[(size_t)node * 64 + lane] =
        r + bias[lane] + extra[(size_t)node * 64 + lane];
  }
}

extern "C" void kernel_launch(void* const* d_in, const int* in_sizes, int n_in,
                              void* d_out, int out_size, void* d_ws, size_t ws_size,
                              hipStream_t stream) {
  const float* x      = (const float*)d_in[0];
  const int*   ei     = (const int*)d_in[1];
  const float* W1     = (const float*)d_in[2];
  const float* a_src1 = (const float*)d_in[3];
  const float* a_dst1 = (const float*)d_in[4];
  const float* b1     = (const float*)d_in[5];
  const float* W2     = (const float*)d_in[6];
  const float* a_src2 = (const float*)d_in[7];
  const float* a_dst2 = (const float*)d_in[8];
  const float* b2     = (const float*)d_in[9];
  const float* Wfc    = (const float*)d_in[10];
  const float* bfc    = (const float*)d_in[11];
  float* out = (float*)d_out;

  const int* esrc = ei;
  const int* edst = ei + N_EDGES;
  const int Et = N_EDGES + N_NODES;

  char* p = (char*)d_ws;
  auto take = [&](size_t bytes) {
    char* r = p;
    p += (bytes + 255) & ~(size_t)255;
    return r;
  };
  float* h1      = (float*)take((size_t)N_NODES * HC * 4);
  float* f1      = (float*)take((size_t)N_NODES * HC * 4);
  float* xch     = (float*)take((size_t)N_NODES * 64 * 4);
  float* al_s    = (float*)take((size_t)N_NODES * 4 * 4);
  float* al_d    = (float*)take((size_t)N_NODES * 4 * 4);
  int*   cnt     = (int*)take((size_t)N_NODES * 4);
  int*   row_ptr = (int*)take((size_t)(N_NODES + 1) * 4);
  int*   wp      = (int*)take((size_t)N_NODES * 4);
  int*   csr     = (int*)take((size_t)Et * 4);
  int*   bsums   = (int*)take(256 * 4);
  float* h2 = h1;  // reuse: h1 dead after conv1 aggregation

  const int nscan = (N_NODES + 1023) / 1024;

  // ---- CSR build (shared by both convs) ----
  init_counts<<<(N_NODES + 255) / 256, 256, 0, stream>>>(cnt, N_NODES);
  count_dst<<<(N_EDGES + 255) / 256, 256, 0, stream>>>(edst, N_EDGES, cnt);
  scan_blocks<<<nscan, 256, 0, stream>>>(cnt, row_ptr, bsums, N_NODES);
  scan_bsums<<<1, 64, 0, stream>>>(bsums, nscan);
  add_back<<<(N_NODES + 256) / 256, 256, 0, stream>>>(row_ptr, bsums, wp, N_NODES, Et);
  scatter_edges<<<(Et + 255) / 256, 256, 0, stream>>>(esrc, edst, N_EDGES, N_NODES, wp, csr);

  const int gx = (N_NODES + 63) / 64;   // 782
  const int gagg = (N_NODES + 3) / 4;   // 12500

  // ---- conv1 ----
  gemm_kernel<<<dim3(gx, HC / 64), 256, 0, stream>>>(x, W1, nullptr, h1, N_NODES, IN_CH, HC);
  al_kernel<<<gagg, 256, 0, stream>>>(h1, a_src1, a_dst1, al_s, al_d, N_NODES);
  agg_kernel<false><<<gagg, 256, 0, stream>>>(h1, al_s, al_d, row_ptr, csr, b1, nullptr, f1, N_NODES);

  // ---- conv2 + residual ----
  gemm_kernel<<<dim3(gx, HC / 64), 256, 0, stream>>>(f1, W2, nullptr, h2, N_NODES, HC, HC);
  al_kernel<<<gagg, 256, 0, stream>>>(h2, a_src2, a_dst2, al_s, al_d, N_NODES);
  gemm_kernel<<<dim3(gx, 1), 256, 0, stream>>>(x, Wfc, bfc, xch, N_NODES, IN_CH, OUT_CC);
  agg_kernel<true><<<gagg, 256, 0, stream>>>(h2, al_s, al_d, row_ptr, csr, b2, xch, out, N_NODES);
}

// Round 8
// 689.388 us; speedup vs baseline: 1.0256x; 1.0256x over previous
//
#include <hip/hip_runtime.h>
#include <math.h>

#define N_NODES 50000
#define N_EDGES 800000
#define IN_CH 128
#define HC 256      // HEADS * OUT_C
#define OUT_CC 64
#define HEADS 4
#define NEG_SLOPE 0.2f

static __device__ __forceinline__ float leaky(float v) {
  return v > 0.f ? v : NEG_SLOPE * v;
}

// ---------------- GEMM: C[M,Nc] = A[M,K] @ B[K,Nc] (+bias) ----------------
// 64x64 tile, 256 threads (16x16), 4x4 micro-tile per thread, BK=64.
__global__ __launch_bounds__(256) void gemm_kernel(
    const float* __restrict__ A, const float* __restrict__ B,
    const float* __restrict__ bias, float* __restrict__ C,
    int M, int K, int Nc) {
  __shared__ float As[64][68];
  __shared__ float Bs[64][68];
  const int bm = blockIdx.x * 64, bn = blockIdx.y * 64;
  const int tid = threadIdx.x;
  const int tr = tid >> 4, tc = tid & 15;
  float acc[4][4] = {};
  for (int k0 = 0; k0 < K; k0 += 64) {
    // stage A tile (64 rows x 64 k) and B tile (64 k x 64 cols)
    for (int i = tid; i < 64 * 16; i += 256) {
      int r = i >> 4, c4 = (i & 15) << 2;
      int gr = bm + r;
      float4 v = make_float4(0.f, 0.f, 0.f, 0.f);
      if (gr < M) v = *(const float4*)(A + (size_t)gr * K + k0 + c4);
      *(float4*)&As[r][c4] = v;
      int gk = k0 + r;
      float4 w = *(const float4*)(B + (size_t)gk * Nc + bn + c4);
      *(float4*)&Bs[r][c4] = w;
    }
    __syncthreads();
    #pragma unroll 16
    for (int kk = 0; kk < 64; ++kk) {
      float a0 = As[tr * 4 + 0][kk];
      float a1 = As[tr * 4 + 1][kk];
      float a2 = As[tr * 4 + 2][kk];
      float a3 = As[tr * 4 + 3][kk];
      float4 b = *(float4*)&Bs[kk][tc * 4];
      acc[0][0] += a0 * b.x; acc[0][1] += a0 * b.y; acc[0][2] += a0 * b.z; acc[0][3] += a0 * b.w;
      acc[1][0] += a1 * b.x; acc[1][1] += a1 * b.y; acc[1][2] += a1 * b.z; acc[1][3] += a1 * b.w;
      acc[2][0] += a2 * b.x; acc[2][1] += a2 * b.y; acc[2][2] += a2 * b.z; acc[2][3] += a2 * b.w;
      acc[3][0] += a3 * b.x; acc[3][1] += a3 * b.y; acc[3][2] += a3 * b.z; acc[3][3] += a3 * b.w;
    }
    __syncthreads();
  }
  float4 bv = make_float4(0.f, 0.f, 0.f, 0.f);
  if (bias) bv = *(const float4*)(bias + bn + tc * 4);
  #pragma unroll
  for (int i = 0; i < 4; ++i) {
    int gr = bm + tr * 4 + i;
    if (gr >= M) continue;
    float4 o = make_float4(acc[i][0] + bv.x, acc[i][1] + bv.y,
                           acc[i][2] + bv.z, acc[i][3] + bv.w);
    *(float4*)(C + (size_t)gr * Nc + bn + tc * 4) = o;
  }
}

// ---------------- per-node attention logits: al[n,h] = <h[n,h,:], a[h,:]> ----------------
__global__ __launch_bounds__(256) void al_kernel(
    const float* __restrict__ hbuf, const float* __restrict__ a_src,
    const float* __restrict__ a_dst, float* __restrict__ al_s,
    float* __restrict__ al_d, int n) {
  int node = blockIdx.x * 4 + (threadIdx.x >> 6);
  int lane = threadIdx.x & 63;
  if (node >= n) return;
  const float* row = hbuf + (size_t)node * HC;
  float s[HEADS], d[HEADS];
  #pragma unroll
  for (int hh = 0; hh < HEADS; ++hh) {
    float v = row[hh * 64 + lane];
    s[hh] = v * a_src[hh * 64 + lane];
    d[hh] = v * a_dst[hh * 64 + lane];
  }
  #pragma unroll
  for (int o = 32; o; o >>= 1) {
    #pragma unroll
    for (int hh = 0; hh < HEADS; ++hh) {
      s[hh] += __shfl_down(s[hh], o);
      d[hh] += __shfl_down(d[hh], o);
    }
  }
  if (lane == 0) {
    *(float4*)(al_s + (size_t)node * 4) = make_float4(s[0], s[1], s[2], s[3]);
    *(float4*)(al_d + (size_t)node * 4) = make_float4(d[0], d[1], d[2], d[3]);
  }
}

// ---------------- CSR build ----------------
__global__ void init_counts(int* __restrict__ cnt, int n) {
  int i = blockIdx.x * blockDim.x + threadIdx.x;
  if (i < n) cnt[i] = 1;  // self loop
}

__global__ void count_dst(const int* __restrict__ dst, int E, int* __restrict__ cnt) {
  int i = blockIdx.x * blockDim.x + threadIdx.x;
  if (i < E) atomicAdd(&cnt[dst[i]], 1);
}

// per-block exclusive scan over 1024-element chunks
__global__ __launch_bounds__(256) void scan_blocks(
    const int* __restrict__ cnt, int* __restrict__ excl,
    int* __restrict__ bsums, int n) {
  __shared__ int ts[256];
  int b = blockIdx.x, tid = threadIdx.x;
  int base = b * 1024 + tid * 4;
  int v[4]; int run = 0;
  #pragma unroll
  for (int j = 0; j < 4; ++j) {
    v[j] = (base + j < n) ? cnt[base + j] : 0;
    run += v[j];
  }
  ts[tid] = run;
  __syncthreads();
  for (int o = 1; o < 256; o <<= 1) {
    int t = (tid >= o) ? ts[tid - o] : 0;
    __syncthreads();
    ts[tid] += t;
    __syncthreads();
  }
  int acc = ts[tid] - run;
  #pragma unroll
  for (int j = 0; j < 4; ++j) {
    if (base + j < n) excl[base + j] = acc;
    acc += v[j];
  }
  if (tid == 255) bsums[b] = ts[255];
}

__global__ void scan_bsums(int* __restrict__ bsums, int nb) {
  if (threadIdx.x == 0 && blockIdx.x == 0) {
    int a = 0;
    for (int i = 0; i < nb; ++i) { int t = bsums[i]; bsums[i] = a; a += t; }
  }
}

__global__ void add_back(int* __restrict__ row_ptr, const int* __restrict__ bsums,
                         int* __restrict__ wp, int n, int total) {
  int i = blockIdx.x * blockDim.x + threadIdx.x;
  if (i < n) {
    int v = row_ptr[i] + bsums[i >> 10];
    row_ptr[i] = v;
    wp[i] = v;
  }
  if (i == n) row_ptr[n] = total;
}

__global__ void scatter_edges(const int* __restrict__ src, const int* __restrict__ dst,
                              int E, int n, int* __restrict__ wp, int* __restrict__ csr) {
  int i = blockIdx.x * blockDim.x + threadIdx.x;
  if (i < E) {
    int p = atomicAdd(&wp[dst[i]], 1);
    csr[p] = src[i];
  } else if (i < E + n) {
    int node = i - E;
    int p = atomicAdd(&wp[node], 1);
    csr[p] = node;
  }
}

// ---------------- GAT aggregation: one wave per dst node, online softmax ----------------
// Lane layout: lane = head*16 + chunk; each lane owns float4 of channels
// [chunk*4 .. chunk*4+3] of its head. Softmax scalar ops issue ONCE per edge
// (2 exp instead of 8), h-row gather is one dwordx4 per lane (1 KB/wave).
template <bool MEAN>
__global__ __launch_bounds__(256) void agg_kernel(
    const float* __restrict__ hbuf, const float* __restrict__ al_s,
    const float* __restrict__ al_d, const int* __restrict__ row_ptr,
    const int* __restrict__ csr_src, const float* __restrict__ bias,
    const float* __restrict__ extra, float* __restrict__ outp, int n) {
  int node = blockIdx.x * 4 + (threadIdx.x >> 6);
  int lane = threadIdx.x & 63;
  if (node >= n) return;
  const int q  = lane >> 4;          // head index 0..3
  const int c4 = (lane & 15) << 2;   // channel base within head
  int beg = row_ptr[node], end = row_ptr[node + 1];
  float ald = al_d[(size_t)node * 4 + q];
  float m = -INFINITY, s = 0.f;
  float4 acc = make_float4(0.f, 0.f, 0.f, 0.f);
  for (int i = beg; i < end; ++i) {
    int src = csr_src[i];
    float als = al_s[(size_t)src * 4 + q];
    float4 hv = *(const float4*)(hbuf + (size_t)src * HC + q * 64 + c4);
    float e = leaky(als + ald);
    float mn = fmaxf(m, e);
    float sc = __expf(m - mn);
    float p  = __expf(e - mn);
    s = s * sc + p;
    acc.x = acc.x * sc + p * hv.x;
    acc.y = acc.y * sc + p * hv.y;
    acc.z = acc.z * sc + p * hv.z;
    acc.w = acc.w * sc + p * hv.w;
    m = mn;
  }
  float inv = 1.0f / (s + 1e-16f);
  if (!MEAN) {
    float4 bv = *(const float4*)(bias + q * 64 + c4);
    float4 o = make_float4(acc.x * inv + bv.x, acc.y * inv + bv.y,
                           acc.z * inv + bv.z, acc.w * inv + bv.w);
    *(float4*)(outp + (size_t)node * HC + q * 64 + c4) = o;
  } else {
    float4 r = make_float4(acc.x * inv, acc.y * inv, acc.z * inv, acc.w * inv);
    // sum across the 4 head-quarters (lanes differing in bits 4,5)
    #pragma unroll
    for (int mask = 16; mask <= 32; mask <<= 1) {
      r.x += __shfl_xor(r.x, mask);
      r.y += __shfl_xor(r.y, mask);
      r.z += __shfl_xor(r.z, mask);
      r.w += __shfl_xor(r.w, mask);
    }
    if (q == 0) {
      float4 bv = *(const float4*)(bias + c4);
      float4 xv = *(const float4*)(extra + (size_t)node * 64 + c4);
      float4 o = make_float4(r.x * 0.25f + bv.x + xv.x,
                             r.y * 0.25f + bv.y + xv.y,
                             r.z * 0.25f + bv.z + xv.z,
                             r.w * 0.25f + bv.w + xv.w);
      *(float4*)(outp + (size_t)node * 64 + c4) = o;
    }
  }
}

extern "C" void kernel_launch(void* const* d_in, const int* in_sizes, int n_in,
                              void* d_out, int out_size, void* d_ws, size_t ws_size,
                              hipStream_t stream) {
  const float* x      = (const float*)d_in[0];
  const int*   ei     = (const int*)d_in[1];
  const float* W1     = (const float*)d_in[2];
  const float* a_src1 = (const float*)d_in[3];
  const float* a_dst1 = (const float*)d_in[4];
  const float* b1     = (const float*)d_in[5];
  const float* W2     = (const float*)d_in[6];
  const float* a_src2 = (const float*)d_in[7];
  const float* a_dst2 = (const float*)d_in[8];
  const float* b2     = (const float*)d_in[9];
  const float* Wfc    = (const float*)d_in[10];
  const float* bfc    = (const float*)d_in[11];
  float* out = (float*)d_out;

  const int* esrc = ei;
  const int* edst = ei + N_EDGES;
  const int Et = N_EDGES + N_NODES;

  char* p = (char*)d_ws;
  auto take = [&](size_t bytes) {
    char* r = p;
    p += (bytes + 255) & ~(size_t)255;
    return r;
  };
  float* h1      = (float*)take((size_t)N_NODES * HC * 4);
  float* f1      = (float*)take((size_t)N_NODES * HC * 4);
  float* xch     = (float*)take((size_t)N_NODES * 64 * 4);
  float* al_s    = (float*)take((size_t)N_NODES * 4 * 4);
  float* al_d    = (float*)take((size_t)N_NODES * 4 * 4);
  int*   cnt     = (int*)take((size_t)N_NODES * 4);
  int*   row_ptr = (int*)take((size_t)(N_NODES + 1) * 4);
  int*   wp      = (int*)take((size_t)N_NODES * 4);
  int*   csr     = (int*)take((size_t)Et * 4);
  int*   bsums   = (int*)take(256 * 4);
  float* h2 = h1;  // reuse: h1 dead after conv1 aggregation

  const int nscan = (N_NODES + 1023) / 1024;

  // ---- CSR build (shared by both convs) ----
  init_counts<<<(N_NODES + 255) / 256, 256, 0, stream>>>(cnt, N_NODES);
  count_dst<<<(N_EDGES + 255) / 256, 256, 0, stream>>>(edst, N_EDGES, cnt);
  scan_blocks<<<nscan, 256, 0, stream>>>(cnt, row_ptr, bsums, N_NODES);
  scan_bsums<<<1, 64, 0, stream>>>(bsums, nscan);
  add_back<<<(N_NODES + 256) / 256, 256, 0, stream>>>(row_ptr, bsums, wp, N_NODES, Et);
  scatter_edges<<<(Et + 255) / 256, 256, 0, stream>>>(esrc, edst, N_EDGES, N_NODES, wp, csr);

  const int gx = (N_NODES + 63) / 64;   // 782
  const int gagg = (N_NODES + 3) / 4;   // 12500

  // ---- conv1 ----
  gemm_kernel<<<dim3(gx, HC / 64), 256, 0, stream>>>(x, W1, nullptr, h1, N_NODES, IN_CH, HC);
  al_kernel<<<gagg, 256, 0, stream>>>(h1, a_src1, a_dst1, al_s, al_d, N_NODES);
  agg_kernel<false><<<gagg, 256, 0, stream>>>(h1, al_s, al_d, row_ptr, csr, b1, nullptr, f1, N_NODES);

  // ---- conv2 + residual ----
  gemm_kernel<<<dim3(gx, HC / 64), 256, 0, stream>>>(f1, W2, nullptr, h2, N_NODES, HC, HC);
  al_kernel<<<gagg, 256, 0, stream>>>(h2, a_src2, a_dst2, al_s, al_d, N_NODES);
  gemm_kernel<<<dim3(gx, 1), 256, 0, stream>>>(x, Wfc, bfc, xch, N_NODES, IN_CH, OUT_CC);
  agg_kernel<true><<<gagg, 256, 0, stream>>>(h2, al_s, al_d, row_ptr, csr, b2, xch, out, N_NODES);
}

// Round 12
// 484.260 us; speedup vs baseline: 1.4600x; 1.4236x over previous
//
#include <hip/hip_runtime.h>
#include <hip/hip_bf16.h>
#include <math.h>

#define N_NODES 50000
#define N_EDGES 800000
#define IN_CH 128
#define HC 256      // HEADS * OUT_C
#define OUT_CC 64
#define HEADS 4
#define NEG_SLOPE 0.2f

typedef __attribute__((ext_vector_type(8))) short bf16x8;
typedef __attribute__((ext_vector_type(4))) float f32x4;

static __device__ __forceinline__ float leaky(float v) {
  return v > 0.f ? v : NEG_SLOPE * v;
}
static __device__ __forceinline__ float bf2f(ushort u) {
  return __uint_as_float((unsigned)u << 16);
}
static __device__ __forceinline__ ushort f2bf(float f) {  // RNE
  unsigned x = __float_as_uint(f);
  return (ushort)((x + 0x7fff + ((x >> 16) & 1)) >> 16);
}

// ---------------- prep: fp32 -> bf16 cast / transposed cast ----------------
__global__ __launch_bounds__(256) void cast_bf16_kernel(
    const float* __restrict__ in, ushort* __restrict__ out, int n) {
  int i = (blockIdx.x * blockDim.x + threadIdx.x) * 4;
  if (i + 3 < n) {
    float4 v = *(const float4*)(in + i);
    *(ushort4*)(out + i) =
        make_ushort4(f2bf(v.x), f2bf(v.y), f2bf(v.z), f2bf(v.w));
  }
}

// W[K][Nc] fp32 -> WT[Nc][K] bf16
__global__ __launch_bounds__(256) void transpose_bf_kernel(
    const float* __restrict__ W, ushort* __restrict__ WT, int K, int Nc) {
  int idx = blockIdx.x * blockDim.x + threadIdx.x;
  if (idx < K * Nc) {
    int nn = idx / K, kk = idx - nn * K;
    WT[idx] = f2bf(W[(size_t)kk * Nc + nn]);
  }
}

// ---------------- bf16 MFMA GEMM: C[M,Nc] = A[M,K] @ B, B given as BT[Nc,K] ----
// 64x64 tile, 256 thr = 4 waves; wave w owns rows w*16..w*16+15 (4 C-frags).
// LDS rows padded to 72 bf16 (144 B) -> 2-way bank aliasing only (free).
__global__ __launch_bounds__(256) void gemm_bf16_kernel(
    const ushort* __restrict__ A, const ushort* __restrict__ BT,
    ushort* __restrict__ C, int M, int K, int Nc) {
  constexpr int PAD = 72;
  __shared__ __align__(16) ushort As[64 * PAD];
  __shared__ __align__(16) ushort Bs[64 * PAD];
  const int bm = blockIdx.x * 64, bn = blockIdx.y * 64;
  const int tid = threadIdx.x;
  const int w = tid >> 6, l = tid & 63;
  const int lr = l & 15;          // A-row / B-col / C-col within frag
  const int lk = (l >> 4) * 8;    // k-base within frag
  f32x4 zero = {0.f, 0.f, 0.f, 0.f};
  f32x4 acc[4] = {zero, zero, zero, zero};
  for (int k0 = 0; k0 < K; k0 += 64) {
    #pragma unroll
    for (int c = 0; c < 2; ++c) {
      int idx = tid + c * 256;            // 0..511
      int r = idx >> 3, c8 = (idx & 7) << 3;
      uint4 av = make_uint4(0u, 0u, 0u, 0u);
      int gr = bm + r;
      if (gr < M) av = *(const uint4*)(A + (size_t)gr * K + k0 + c8);
      *(uint4*)&As[r * PAD + c8] = av;
      uint4 bv = *(const uint4*)(BT + (size_t)(bn + r) * K + k0 + c8);
      *(uint4*)&Bs[r * PAD + c8] = bv;
    }
    __syncthreads();
    #pragma unroll
    for (int kk = 0; kk < 2; ++kk) {
      bf16x8 a = *(const bf16x8*)&As[(w * 16 + lr) * PAD + kk * 32 + lk];
      #pragma unroll
      for (int fc = 0; fc < 4; ++fc) {
        bf16x8 b = *(const bf16x8*)&Bs[(fc * 16 + lr) * PAD + kk * 32 + lk];
        acc[fc] = __builtin_amdgcn_mfma_f32_16x16x32_bf16(a, b, acc[fc], 0, 0, 0);
      }
    }
    __syncthreads();
  }
  const int cr = (l >> 4) * 4;
  #pragma unroll
  for (int fc = 0; fc < 4; ++fc) {
    #pragma unroll
    for (int j = 0; j < 4; ++j) {
      int r = bm + w * 16 + cr + j;
      if (r < M) C[(size_t)r * Nc + bn + fc * 16 + lr] = f2bf(acc[fc][j]);
    }
  }
}

// ---------------- fp32 GEMM (residual fc only): C = A @ B + bias ----------------
__global__ __launch_bounds__(256) void gemm_kernel(
    const float* __restrict__ A, const float* __restrict__ B,
    const float* __restrict__ bias, float* __restrict__ C,
    int M, int K, int Nc) {
  __shared__ float As[64][68];
  __shared__ float Bs[64][68];
  const int bm = blockIdx.x * 64, bn = blockIdx.y * 64;
  const int tid = threadIdx.x;
  const int tr = tid >> 4, tc = tid & 15;
  float acc[4][4] = {};
  for (int k0 = 0; k0 < K; k0 += 64) {
    for (int i = tid; i < 64 * 16; i += 256) {
      int r = i >> 4, c4 = (i & 15) << 2;
      int gr = bm + r;
      float4 v = make_float4(0.f, 0.f, 0.f, 0.f);
      if (gr < M) v = *(const float4*)(A + (size_t)gr * K + k0 + c4);
      *(float4*)&As[r][c4] = v;
      int gk = k0 + r;
      float4 wv = *(const float4*)(B + (size_t)gk * Nc + bn + c4);
      *(float4*)&Bs[r][c4] = wv;
    }
    __syncthreads();
    #pragma unroll 16
    for (int kk = 0; kk < 64; ++kk) {
      float a0 = As[tr * 4 + 0][kk];
      float a1 = As[tr * 4 + 1][kk];
      float a2 = As[tr * 4 + 2][kk];
      float a3 = As[tr * 4 + 3][kk];
      float4 b = *(float4*)&Bs[kk][tc * 4];
      acc[0][0] += a0 * b.x; acc[0][1] += a0 * b.y; acc[0][2] += a0 * b.z; acc[0][3] += a0 * b.w;
      acc[1][0] += a1 * b.x; acc[1][1] += a1 * b.y; acc[1][2] += a1 * b.z; acc[1][3] += a1 * b.w;
      acc[2][0] += a2 * b.x; acc[2][1] += a2 * b.y; acc[2][2] += a2 * b.z; acc[2][3] += a2 * b.w;
      acc[3][0] += a3 * b.x; acc[3][1] += a3 * b.y; acc[3][2] += a3 * b.z; acc[3][3] += a3 * b.w;
    }
    __syncthreads();
  }
  float4 bv = make_float4(0.f, 0.f, 0.f, 0.f);
  if (bias) bv = *(const float4*)(bias + bn + tc * 4);
  #pragma unroll
  for (int i = 0; i < 4; ++i) {
    int gr = bm + tr * 4 + i;
    if (gr >= M) continue;
    float4 o = make_float4(acc[i][0] + bv.x, acc[i][1] + bv.y,
                           acc[i][2] + bv.z, acc[i][3] + bv.w);
    *(float4*)(C + (size_t)gr * Nc + bn + tc * 4) = o;
  }
}

// ---------------- per-node attention logits from bf16 h ----------------
// lane covers channels lane*4..lane*4+3 (all within head lane>>4).
__global__ __launch_bounds__(256) void al_kernel_bf(
    const ushort* __restrict__ h, const float* __restrict__ a_src,
    const float* __restrict__ a_dst, float* __restrict__ al_s,
    float* __restrict__ al_d, int n) {
  int node = blockIdx.x * 4 + (threadIdx.x >> 6);
  int lane = threadIdx.x & 63;
  if (node >= n) return;
  ushort4 hv = *(const ushort4*)(h + (size_t)node * HC + lane * 4);
  float4 a4 = *(const float4*)(a_src + lane * 4);
  float4 d4 = *(const float4*)(a_dst + lane * 4);
  float hx = bf2f(hv.x), hy = bf2f(hv.y), hz = bf2f(hv.z), hw = bf2f(hv.w);
  float s = hx * a4.x + hy * a4.y + hz * a4.z + hw * a4.w;
  float d = hx * d4.x + hy * d4.y + hz * d4.z + hw * d4.w;
  #pragma unroll
  for (int o = 1; o < 16; o <<= 1) {
    s += __shfl_xor(s, o);
    d += __shfl_xor(d, o);
  }
  if ((lane & 15) == 0) {
    al_s[(size_t)node * 4 + (lane >> 4)] = s;
    al_d[(size_t)node * 4 + (lane >> 4)] = d;
  }
}

// ---------------- CSR build ----------------
__global__ void init_counts(int* __restrict__ cnt, int n) {
  int i = blockIdx.x * blockDim.x + threadIdx.x;
  if (i < n) cnt[i] = 1;  // self loop
}

__global__ void count_dst(const int* __restrict__ dst, int E, int* __restrict__ cnt) {
  int i = blockIdx.x * blockDim.x + threadIdx.x;
  if (i < E) atomicAdd(&cnt[dst[i]], 1);
}

__global__ __launch_bounds__(256) void scan_blocks(
    const int* __restrict__ cnt, int* __restrict__ excl,
    int* __restrict__ bsums, int n) {
  __shared__ int ts[256];
  int b = blockIdx.x, tid = threadIdx.x;
  int base = b * 1024 + tid * 4;
  int v[4]; int run = 0;
  #pragma unroll
  for (int j = 0; j < 4; ++j) {
    v[j] = (base + j < n) ? cnt[base + j] : 0;
    run += v[j];
  }
  ts[tid] = run;
  __syncthreads();
  for (int o = 1; o < 256; o <<= 1) {
    int t = (tid >= o) ? ts[tid - o] : 0;
    __syncthreads();
    ts[tid] += t;
    __syncthreads();
  }
  int acc = ts[tid] - run;
  #pragma unroll
  for (int j = 0; j < 4; ++j) {
    if (base + j < n) excl[base + j] = acc;
    acc += v[j];
  }
  if (tid == 255) bsums[b] = ts[255];
}

__global__ void scan_bsums(int* __restrict__ bsums, int nb) {
  if (threadIdx.x == 0 && blockIdx.x == 0) {
    int a = 0;
    for (int i = 0; i < nb; ++i) { int t = bsums[i]; bsums[i] = a; a += t; }
  }
}

__global__ void add_back(int* __restrict__ row_ptr, const int* __restrict__ bsums,
                         int* __restrict__ wp, int n, int total) {
  int i = blockIdx.x * blockDim.x + threadIdx.x;
  if (i < n) {
    int v = row_ptr[i] + bsums[i >> 10];
    row_ptr[i] = v;
    wp[i] = v;
  }
  if (i == n) row_ptr[n] = total;
}

__global__ void scatter_edges(const int* __restrict__ src, const int* __restrict__ dst,
                              int E, int n, int* __restrict__ wp, int* __restrict__ csr) {
  int i = blockIdx.x * blockDim.x + threadIdx.x;
  if (i < E) {
    int p = atomicAdd(&wp[dst[i]], 1);
    csr[p] = src[i];
  } else if (i < E + n) {
    int node = i - E;
    int p = atomicAdd(&wp[node], 1);
    csr[p] = node;
  }
}

// ---------------- GAT aggregation: one wave per dst node, online softmax ------
// h in bf16 (8 B gather per lane). lane = head*16 + chunk; lane owns 4 channels.
// MEAN=false: writes bf16 f1 (+bias). MEAN=true: head-mean + bias + extra, fp32.
template <bool MEAN>
__global__ __launch_bounds__(256) void agg_kernel(
    const ushort* __restrict__ hbuf, const float* __restrict__ al_s,
    const float* __restrict__ al_d, const int* __restrict__ row_ptr,
    const int* __restrict__ csr_src, const float* __restrict__ bias,
    const float* __restrict__ extra, void* __restrict__ outp, int n) {
  int node = blockIdx.x * 4 + (threadIdx.x >> 6);
  int lane = threadIdx.x & 63;
  if (node >= n) return;
  const int q  = lane >> 4;          // head
  const int c4 = (lane & 15) << 2;   // channel base within head
  int beg = row_ptr[node], end = row_ptr[node + 1];
  float ald = al_d[(size_t)node * 4 + q];
  float m = -INFINITY, s = 0.f;
  float4 acc = make_float4(0.f, 0.f, 0.f, 0.f);
  for (int i = beg; i < end; ++i) {
    int src = csr_src[i];
    float als = al_s[(size_t)src * 4 + q];
    ushort4 hv4 = *(const ushort4*)(hbuf + (size_t)src * HC + q * 64 + c4);
    float e = leaky(als + ald);
    float mn = fmaxf(m, e);
    float sc = __expf(m - mn);
    float p  = __expf(e - mn);
    s = s * sc + p;
    acc.x = acc.x * sc + p * bf2f(hv4.x);
    acc.y = acc.y * sc + p * bf2f(hv4.y);
    acc.z = acc.z * sc + p * bf2f(hv4.z);
    acc.w = acc.w * sc + p * bf2f(hv4.w);
    m = mn;
  }
  float inv = 1.0f / (s + 1e-16f);
  if (!MEAN) {
    float4 bv = *(const float4*)(bias + q * 64 + c4);
    ushort* o = (ushort*)outp + (size_t)node * HC + q * 64 + c4;
    *(ushort4*)o = make_ushort4(f2bf(acc.x * inv + bv.x),
                                f2bf(acc.y * inv + bv.y),
                                f2bf(acc.z * inv + bv.z),
                                f2bf(acc.w * inv + bv.w));
  } else {
    float4 r = make_float4(acc.x * inv, acc.y * inv, acc.z * inv, acc.w * inv);
    #pragma unroll
    for (int mask = 16; mask <= 32; mask <<= 1) {
      r.x += __shfl_xor(r.x, mask);
      r.y += __shfl_xor(r.y, mask);
      r.z += __shfl_xor(r.z, mask);
      r.w += __shfl_xor(r.w, mask);
    }
    if (q == 0) {
      float4 bv = *(const float4*)(bias + c4);
      float4 xv = *(const float4*)(extra + (size_t)node * 64 + c4);
      float* o = (float*)outp + (size_t)node * 64 + c4;
      *(float4*)o = make_float4(r.x * 0.25f + bv.x + xv.x,
                                r.y * 0.25f + bv.y + xv.y,
                                r.z * 0.25f + bv.z + xv.z,
                                r.w * 0.25f + bv.w + xv.w);
    }
  }
}

extern "C" void kernel_launch(void* const* d_in, const int* in_sizes, int n_in,
                              void* d_out, int out_size, void* d_ws, size_t ws_size,
                              hipStream_t stream) {
  const float* x      = (const float*)d_in[0];
  const int*   ei     = (const int*)d_in[1];
  const float* W1     = (const float*)d_in[2];
  const float* a_src1 = (const float*)d_in[3];
  const float* a_dst1 = (const float*)d_in[4];
  const float* b1     = (const float*)d_in[5];
  const float* W2     = (const float*)d_in[6];
  const float* a_src2 = (const float*)d_in[7];
  const float* a_dst2 = (const float*)d_in[8];
  const float* b2     = (const float*)d_in[9];
  const float* Wfc    = (const float*)d_in[10];
  const float* bfc    = (const float*)d_in[11];
  float* out = (float*)d_out;

  const int* esrc = ei;
  const int* edst = ei + N_EDGES;
  const int Et = N_EDGES + N_NODES;

  char* p = (char*)d_ws;
  auto take = [&](size_t bytes) {
    char* r = p;
    p += (bytes + 255) & ~(size_t)255;
    return r;
  };
  ushort* x_bf    = (ushort*)take((size_t)N_NODES * IN_CH * 2);
  ushort* h_bf    = (ushort*)take((size_t)N_NODES * HC * 2);   // h1, then h2
  ushort* f1_bf   = (ushort*)take((size_t)N_NODES * HC * 2);
  ushort* W1T     = (ushort*)take((size_t)IN_CH * HC * 2);
  ushort* W2T     = (ushort*)take((size_t)HC * HC * 2);
  float*  xch     = (float*)take((size_t)N_NODES * 64 * 4);
  float*  al_s    = (float*)take((size_t)N_NODES * 4 * 4);
  float*  al_d    = (float*)take((size_t)N_NODES * 4 * 4);
  int*    cnt     = (int*)take((size_t)N_NODES * 4);
  int*    row_ptr = (int*)take((size_t)(N_NODES + 1) * 4);
  int*    wp      = (int*)take((size_t)N_NODES * 4);
  int*    csr     = (int*)take((size_t)Et * 4);
  int*    bsums   = (int*)take(256 * 4);

  const int nscan = (N_NODES + 1023) / 1024;
  const int gx = (N_NODES + 63) / 64;   // 782
  const int gagg = (N_NODES + 3) / 4;   // 12500

  // ---- prep: bf16 casts + W transposes (independent) ----
  cast_bf16_kernel<<<(N_NODES * IN_CH / 4 + 255) / 256, 256, 0, stream>>>(
      x, x_bf, N_NODES * IN_CH);
  transpose_bf_kernel<<<(IN_CH * HC + 255) / 256, 256, 0, stream>>>(W1, W1T, IN_CH, HC);
  transpose_bf_kernel<<<(HC * HC + 255) / 256, 256, 0, stream>>>(W2, W2T, HC, HC);

  // ---- CSR build (shared by both convs) ----
  init_counts<<<(N_NODES + 255) / 256, 256, 0, stream>>>(cnt, N_NODES);
  count_dst<<<(N_EDGES + 255) / 256, 256, 0, stream>>>(edst, N_EDGES, cnt);
  scan_blocks<<<nscan, 256, 0, stream>>>(cnt, row_ptr, bsums, N_NODES);
  scan_bsums<<<1, 64, 0, stream>>>(bsums, nscan);
  add_back<<<(N_NODES + 256) / 256, 256, 0, stream>>>(row_ptr, bsums, wp, N_NODES, Et);
  scatter_edges<<<(Et + 255) / 256, 256, 0, stream>>>(esrc, edst, N_EDGES, N_NODES, wp, csr);

  // ---- conv1 (bf16 MFMA) ----
  gemm_bf16_kernel<<<dim3(gx, HC / 64), 256, 0, stream>>>(
      x_bf, W1T, h_bf, N_NODES, IN_CH, HC);
  al_kernel_bf<<<gagg, 256, 0, stream>>>(h_bf, a_src1, a_dst1, al_s, al_d, N_NODES);
  agg_kernel<false><<<gagg, 256, 0, stream>>>(h_bf, al_s, al_d, row_ptr, csr,
                                              b1, nullptr, f1_bf, N_NODES);

  // ---- conv2 (bf16 MFMA) + residual ----
  gemm_bf16_kernel<<<dim3(gx, HC / 64), 256, 0, stream>>>(
      f1_bf, W2T, h_bf, N_NODES, HC, HC);
  al_kernel_bf<<<gagg, 256, 0, stream>>>(h_bf, a_src2, a_dst2, al_s, al_d, N_NODES);
  gemm_kernel<<<dim3(gx, 1), 256, 0, stream>>>(x, Wfc, bfc, xch, N_NODES, IN_CH, OUT_CC);
  agg_kernel<true><<<gagg, 256, 0, stream>>>(h_bf, al_s, al_d, row_ptr, csr,
                                             b2, xch, out, N_NODES);
}

// Round 15
// 409.554 us; speedup vs baseline: 1.7263x; 1.1824x over previous
//
#include <hip/hip_runtime.h>
#include <hip/hip_bf16.h>
#include <math.h>

#define N_NODES 50000
#define N_EDGES 800000
#define IN_CH 128
#define HC 256      // HEADS * OUT_C
#define OUT_CC 64
#define HEADS 4
#define NEG_SLOPE 0.2f

typedef __attribute__((ext_vector_type(8))) short bf16x8;
typedef __attribute__((ext_vector_type(4))) float f32x4;

static __device__ __forceinline__ float leaky(float v) {
  return v > 0.f ? v : NEG_SLOPE * v;
}
static __device__ __forceinline__ float bf2f(ushort u) {
  return __uint_as_float((unsigned)u << 16);
}
static __device__ __forceinline__ ushort f2bf(float f) {  // RNE
  unsigned x = __float_as_uint(f);
  return (ushort)((x + 0x7fff + ((x >> 16) & 1)) >> 16);
}

// ---------------- prep: fp32 -> bf16 cast / transposed cast ----------------
__global__ __launch_bounds__(256) void cast_bf16_kernel(
    const float* __restrict__ in, ushort* __restrict__ out, int n) {
  int i = (blockIdx.x * blockDim.x + threadIdx.x) * 4;
  if (i + 3 < n) {
    float4 v = *(const float4*)(in + i);
    *(ushort4*)(out + i) =
        make_ushort4(f2bf(v.x), f2bf(v.y), f2bf(v.z), f2bf(v.w));
  }
}

// W[K][Nc] fp32 -> WT[Nc][K] bf16
__global__ __launch_bounds__(256) void transpose_bf_kernel(
    const float* __restrict__ W, ushort* __restrict__ WT, int K, int Nc) {
  int idx = blockIdx.x * blockDim.x + threadIdx.x;
  if (idx < K * Nc) {
    int nn = idx / K, kk = idx - nn * K;
    WT[idx] = f2bf(W[(size_t)kk * Nc + nn]);
  }
}

// ---------------- bf16 MFMA GEMM: C[M,Nc] = A[M,K] @ B, B given as BT[Nc,K] ----
__global__ __launch_bounds__(256) void gemm_bf16_kernel(
    const ushort* __restrict__ A, const ushort* __restrict__ BT,
    ushort* __restrict__ C, int M, int K, int Nc) {
  constexpr int PAD = 72;
  __shared__ __align__(16) ushort As[64 * PAD];
  __shared__ __align__(16) ushort Bs[64 * PAD];
  const int bm = blockIdx.x * 64, bn = blockIdx.y * 64;
  const int tid = threadIdx.x;
  const int w = tid >> 6, l = tid & 63;
  const int lr = l & 15;          // A-row / B-col / C-col within frag
  const int lk = (l >> 4) * 8;    // k-base within frag
  f32x4 zero = {0.f, 0.f, 0.f, 0.f};
  f32x4 acc[4] = {zero, zero, zero, zero};
  for (int k0 = 0; k0 < K; k0 += 64) {
    #pragma unroll
    for (int c = 0; c < 2; ++c) {
      int idx = tid + c * 256;            // 0..511
      int r = idx >> 3, c8 = (idx & 7) << 3;
      uint4 av = make_uint4(0u, 0u, 0u, 0u);
      int gr = bm + r;
      if (gr < M) av = *(const uint4*)(A + (size_t)gr * K + k0 + c8);
      *(uint4*)&As[r * PAD + c8] = av;
      uint4 bv = *(const uint4*)(BT + (size_t)(bn + r) * K + k0 + c8);
      *(uint4*)&Bs[r * PAD + c8] = bv;
    }
    __syncthreads();
    #pragma unroll
    for (int kk = 0; kk < 2; ++kk) {
      bf16x8 a = *(const bf16x8*)&As[(w * 16 + lr) * PAD + kk * 32 + lk];
      #pragma unroll
      for (int fc = 0; fc < 4; ++fc) {
        bf16x8 b = *(const bf16x8*)&Bs[(fc * 16 + lr) * PAD + kk * 32 + lk];
        acc[fc] = __builtin_amdgcn_mfma_f32_16x16x32_bf16(a, b, acc[fc], 0, 0, 0);
      }
    }
    __syncthreads();
  }
  const int cr = (l >> 4) * 4;
  #pragma unroll
  for (int fc = 0; fc < 4; ++fc) {
    #pragma unroll
    for (int j = 0; j < 4; ++j) {
      int r = bm + w * 16 + cr + j;
      if (r < M) C[(size_t)r * Nc + bn + fc * 16 + lr] = f2bf(acc[fc][j]);
    }
  }
}

// ---------------- fp32 GEMM (residual fc only): C = A @ B + bias ----------------
__global__ __launch_bounds__(256) void gemm_kernel(
    const float* __restrict__ A, const float* __restrict__ B,
    const float* __restrict__ bias, float* __restrict__ C,
    int M, int K, int Nc) {
  __shared__ float As[64][68];
  __shared__ float Bs[64][68];
  const int bm = blockIdx.x * 64, bn = blockIdx.y * 64;
  const int tid = threadIdx.x;
  const int tr = tid >> 4, tc = tid & 15;
  float acc[4][4] = {};
  for (int k0 = 0; k0 < K; k0 += 64) {
    for (int i = tid; i < 64 * 16; i += 256) {
      int r = i >> 4, c4 = (i & 15) << 2;
      int gr = bm + r;
      float4 v = make_float4(0.f, 0.f, 0.f, 0.f);
      if (gr < M) v = *(const float4*)(A + (size_t)gr * K + k0 + c4);
      *(float4*)&As[r][c4] = v;
      int gk = k0 + r;
      float4 wv = *(const float4*)(B + (size_t)gk * Nc + bn + c4);
      *(float4*)&Bs[r][c4] = wv;
    }
    __syncthreads();
    #pragma unroll 16
    for (int kk = 0; kk < 64; ++kk) {
      float a0 = As[tr * 4 + 0][kk];
      float a1 = As[tr * 4 + 1][kk];
      float a2 = As[tr * 4 + 2][kk];
      float a3 = As[tr * 4 + 3][kk];
      float4 b = *(float4*)&Bs[kk][tc * 4];
      acc[0][0] += a0 * b.x; acc[0][1] += a0 * b.y; acc[0][2] += a0 * b.z; acc[0][3] += a0 * b.w;
      acc[1][0] += a1 * b.x; acc[1][1] += a1 * b.y; acc[1][2] += a1 * b.z; acc[1][3] += a1 * b.w;
      acc[2][0] += a2 * b.x; acc[2][1] += a2 * b.y; acc[2][2] += a2 * b.z; acc[2][3] += a2 * b.w;
      acc[3][0] += a3 * b.x; acc[3][1] += a3 * b.y; acc[3][2] += a3 * b.z; acc[3][3] += a3 * b.w;
    }
    __syncthreads();
  }
  float4 bv = make_float4(0.f, 0.f, 0.f, 0.f);
  if (bias) bv = *(const float4*)(bias + bn + tc * 4);
  #pragma unroll
  for (int i = 0; i < 4; ++i) {
    int gr = bm + tr * 4 + i;
    if (gr >= M) continue;
    float4 o = make_float4(acc[i][0] + bv.x, acc[i][1] + bv.y,
                           acc[i][2] + bv.z, acc[i][3] + bv.w);
    *(float4*)(C + (size_t)gr * Nc + bn + tc * 4) = o;
  }
}

// ---------------- per-node attention logits from bf16 h ----------------
__global__ __launch_bounds__(256) void al_kernel_bf(
    const ushort* __restrict__ h, const float* __restrict__ a_src,
    const float* __restrict__ a_dst, float* __restrict__ al_s,
    float* __restrict__ al_d, int n) {
  int node = blockIdx.x * 4 + (threadIdx.x >> 6);
  int lane = threadIdx.x & 63;
  if (node >= n) return;
  ushort4 hv = *(const ushort4*)(h + (size_t)node * HC + lane * 4);
  float4 a4 = *(const float4*)(a_src + lane * 4);
  float4 d4 = *(const float4*)(a_dst + lane * 4);
  float hx = bf2f(hv.x), hy = bf2f(hv.y), hz = bf2f(hv.z), hw = bf2f(hv.w);
  float s = hx * a4.x + hy * a4.y + hz * a4.z + hw * a4.w;
  float d = hx * d4.x + hy * d4.y + hz * d4.z + hw * d4.w;
  #pragma unroll
  for (int o = 1; o < 16; o <<= 1) {
    s += __shfl_xor(s, o);
    d += __shfl_xor(d, o);
  }
  if ((lane & 15) == 0) {
    al_s[(size_t)node * 4 + (lane >> 4)] = s;
    al_d[(size_t)node * 4 + (lane >> 4)] = d;
  }
}

// ---------------- CSR build ----------------
__global__ void init_counts(int* __restrict__ cnt, int n) {
  int i = blockIdx.x * blockDim.x + threadIdx.x;
  if (i < n) cnt[i] = 1;  // self loop
}

__global__ void count_dst(const int* __restrict__ dst, int E, int* __restrict__ cnt) {
  int i = blockIdx.x * blockDim.x + threadIdx.x;
  if (i < E) atomicAdd(&cnt[dst[i]], 1);
}

__global__ __launch_bounds__(256) void scan_blocks(
    const int* __restrict__ cnt, int* __restrict__ excl,
    int* __restrict__ bsums, int n) {
  __shared__ int ts[256];
  int b = blockIdx.x, tid = threadIdx.x;
  int base = b * 1024 + tid * 4;
  int v[4]; int run = 0;
  #pragma unroll
  for (int j = 0; j < 4; ++j) {
    v[j] = (base + j < n) ? cnt[base + j] : 0;
    run += v[j];
  }
  ts[tid] = run;
  __syncthreads();
  for (int o = 1; o < 256; o <<= 1) {
    int t = (tid >= o) ? ts[tid - o] : 0;
    __syncthreads();
    ts[tid] += t;
    __syncthreads();
  }
  int acc = ts[tid] - run;
  #pragma unroll
  for (int j = 0; j < 4; ++j) {
    if (base + j < n) excl[base + j] = acc;
    acc += v[j];
  }
  if (tid == 255) bsums[b] = ts[255];
}

__global__ void scan_bsums(int* __restrict__ bsums, int nb) {
  if (threadIdx.x == 0 && blockIdx.x == 0) {
    int a = 0;
    for (int i = 0; i < nb; ++i) { int t = bsums[i]; bsums[i] = a; a += t; }
  }
}

__global__ void add_back(int* __restrict__ row_ptr, const int* __restrict__ bsums,
                         int* __restrict__ wp, int n, int total) {
  int i = blockIdx.x * blockDim.x + threadIdx.x;
  if (i < n) {
    int v = row_ptr[i] + bsums[i >> 10];
    row_ptr[i] = v;
    wp[i] = v;
  }
  if (i == n) row_ptr[n] = total;
}

__global__ void scatter_edges(const int* __restrict__ src, const int* __restrict__ dst,
                              int E, int n, int* __restrict__ wp, int* __restrict__ csr) {
  int i = blockIdx.x * blockDim.x + threadIdx.x;
  if (i < E) {
    int p = atomicAdd(&wp[dst[i]], 1);
    csr[p] = src[i];
  } else if (i < E + n) {
    int node = i - E;
    int p = atomicAdd(&wp[node], 1);
    csr[p] = node;
  }
}

// ---------------- GAT aggregation: one wave per dst node, online softmax ------
// h bf16 (8 B/lane gather). lane = head*16 + chunk; lane owns 4 channels.
// Edge loop unrolled x4 with grouped loads (8 gathers in flight) and ONE
// rescale per group: mn = max(m, e0..e3); acc = acc*sc + sum p_j*h_j.
template <bool MEAN>
__global__ __launch_bounds__(256) void agg_kernel(
    const ushort* __restrict__ hbuf, const float* __restrict__ al_s,
    const float* __restrict__ al_d, const int* __restrict__ row_ptr,
    const int* __restrict__ csr_src, const float* __restrict__ bias,
    const float* __restrict__ extra, void* __restrict__ outp, int n) {
  int node = blockIdx.x * 4 + (threadIdx.x >> 6);
  int lane = threadIdx.x & 63;
  if (node >= n) return;
  const int q  = lane >> 4;          // head
  const int c4 = (lane & 15) << 2;   // channel base within head
  const int beg = row_ptr[node], end = row_ptr[node + 1];
  const float ald = al_d[(size_t)node * 4 + q];
  float m = -INFINITY, s = 0.f;
  float4 acc = make_float4(0.f, 0.f, 0.f, 0.f);

  int i = beg;
  for (; i + 3 < end; i += 4) {
    // issue all loads up front -> 4-deep MLP
    int s0 = csr_src[i + 0];
    int s1 = csr_src[i + 1];
    int s2 = csr_src[i + 2];
    int s3 = csr_src[i + 3];
    float a0 = al_s[(size_t)s0 * 4 + q];
    float a1 = al_s[(size_t)s1 * 4 + q];
    float a2 = al_s[(size_t)s2 * 4 + q];
    float a3 = al_s[(size_t)s3 * 4 + q];
    ushort4 h0 = *(const ushort4*)(hbuf + (size_t)s0 * HC + q * 64 + c4);
    ushort4 h1 = *(const ushort4*)(hbuf + (size_t)s1 * HC + q * 64 + c4);
    ushort4 h2 = *(const ushort4*)(hbuf + (size_t)s2 * HC + q * 64 + c4);
    ushort4 h3 = *(const ushort4*)(hbuf + (size_t)s3 * HC + q * 64 + c4);
    float e0 = leaky(a0 + ald);
    float e1 = leaky(a1 + ald);
    float e2 = leaky(a2 + ald);
    float e3 = leaky(a3 + ald);
    float mn = fmaxf(fmaxf(fmaxf(e0, e1), fmaxf(e2, e3)), m);
    float sc = __expf(m - mn);
    float p0 = __expf(e0 - mn);
    float p1 = __expf(e1 - mn);
    float p2 = __expf(e2 - mn);
    float p3 = __expf(e3 - mn);
    s = s * sc + (p0 + p1 + p2 + p3);
    acc.x = acc.x * sc + p0 * bf2f(h0.x) + p1 * bf2f(h1.x) + p2 * bf2f(h2.x) + p3 * bf2f(h3.x);
    acc.y = acc.y * sc + p0 * bf2f(h0.y) + p1 * bf2f(h1.y) + p2 * bf2f(h2.y) + p3 * bf2f(h3.y);
    acc.z = acc.z * sc + p0 * bf2f(h0.z) + p1 * bf2f(h1.z) + p2 * bf2f(h2.z) + p3 * bf2f(h3.z);
    acc.w = acc.w * sc + p0 * bf2f(h0.w) + p1 * bf2f(h1.w) + p2 * bf2f(h2.w) + p3 * bf2f(h3.w);
    m = mn;
  }
  for (; i < end; ++i) {  // tail (0..3 edges; self-loop guarantees end > beg)
    int src = csr_src[i];
    float als = al_s[(size_t)src * 4 + q];
    ushort4 hv4 = *(const ushort4*)(hbuf + (size_t)src * HC + q * 64 + c4);
    float e = leaky(als + ald);
    float mn = fmaxf(m, e);
    float sc = __expf(m - mn);
    float p  = __expf(e - mn);
    s = s * sc + p;
    acc.x = acc.x * sc + p * bf2f(hv4.x);
    acc.y = acc.y * sc + p * bf2f(hv4.y);
    acc.z = acc.z * sc + p * bf2f(hv4.z);
    acc.w = acc.w * sc + p * bf2f(hv4.w);
    m = mn;
  }

  float inv = 1.0f / (s + 1e-16f);
  if (!MEAN) {
    float4 bv = *(const float4*)(bias + q * 64 + c4);
    ushort* o = (ushort*)outp + (size_t)node * HC + q * 64 + c4;
    *(ushort4*)o = make_ushort4(f2bf(acc.x * inv + bv.x),
                                f2bf(acc.y * inv + bv.y),
                                f2bf(acc.z * inv + bv.z),
                                f2bf(acc.w * inv + bv.w));
  } else {
    float4 r = make_float4(acc.x * inv, acc.y * inv, acc.z * inv, acc.w * inv);
    #pragma unroll
    for (int mask = 16; mask <= 32; mask <<= 1) {
      r.x += __shfl_xor(r.x, mask);
      r.y += __shfl_xor(r.y, mask);
      r.z += __shfl_xor(r.z, mask);
      r.w += __shfl_xor(r.w, mask);
    }
    if (q == 0) {
      float4 bv = *(const float4*)(bias + c4);
      float4 xv = *(const float4*)(extra + (size_t)node * 64 + c4);
      float* o = (float*)outp + (size_t)node * 64 + c4;
      *(float4*)o = make_float4(r.x * 0.25f + bv.x + xv.x,
                                r.y * 0.25f + bv.y + xv.y,
                                r.z * 0.25f + bv.z + xv.z,
                                r.w * 0.25f + bv.w + xv.w);
    }
  }
}

extern "C" void kernel_launch(void* const* d_in, const int* in_sizes, int n_in,
                              void* d_out, int out_size, void* d_ws, size_t ws_size,
                              hipStream_t stream) {
  const float* x      = (const float*)d_in[0];
  const int*   ei     = (const int*)d_in[1];
  const float* W1     = (const float*)d_in[2];
  const float* a_src1 = (const float*)d_in[3];
  const float* a_dst1 = (const float*)d_in[4];
  const float* b1     = (const float*)d_in[5];
  const float* W2     = (const float*)d_in[6];
  const float* a_src2 = (const float*)d_in[7];
  const float* a_dst2 = (const float*)d_in[8];
  const float* b2     = (const float*)d_in[9];
  const float* Wfc    = (const float*)d_in[10];
  const float* bfc    = (const float*)d_in[11];
  float* out = (float*)d_out;

  const int* esrc = ei;
  const int* edst = ei + N_EDGES;
  const int Et = N_EDGES + N_NODES;

  char* p = (char*)d_ws;
  auto take = [&](size_t bytes) {
    char* r = p;
    p += (bytes + 255) & ~(size_t)255;
    return r;
  };
  ushort* x_bf    = (ushort*)take((size_t)N_NODES * IN_CH * 2);
  ushort* h_bf    = (ushort*)take((size_t)N_NODES * HC * 2);   // h1, then h2
  ushort* f1_bf   = (ushort*)take((size_t)N_NODES * HC * 2);
  ushort* W1T     = (ushort*)take((size_t)IN_CH * HC * 2);
  ushort* W2T     = (ushort*)take((size_t)HC * HC * 2);
  float*  xch     = (float*)take((size_t)N_NODES * 64 * 4);
  float*  al_s    = (float*)take((size_t)N_NODES * 4 * 4);
  float*  al_d    = (float*)take((size_t)N_NODES * 4 * 4);
  int*    cnt     = (int*)take((size_t)N_NODES * 4);
  int*    row_ptr = (int*)take((size_t)(N_NODES + 1) * 4);
  int*    wp      = (int*)take((size_t)N_NODES * 4);
  int*    csr     = (int*)take((size_t)Et * 4);
  int*    bsums   = (int*)take(256 * 4);

  const int nscan = (N_NODES + 1023) / 1024;
  const int gx = (N_NODES + 63) / 64;   // 782
  const int gagg = (N_NODES + 3) / 4;   // 12500

  // ---- prep: bf16 casts + W transposes (independent) ----
  cast_bf16_kernel<<<(N_NODES * IN_CH / 4 + 255) / 256, 256, 0, stream>>>(
      x, x_bf, N_NODES * IN_CH);
  transpose_bf_kernel<<<(IN_CH * HC + 255) / 256, 256, 0, stream>>>(W1, W1T, IN_CH, HC);
  transpose_bf_kernel<<<(HC * HC + 255) / 256, 256, 0, stream>>>(W2, W2T, HC, HC);

  // ---- CSR build (shared by both convs) ----
  init_counts<<<(N_NODES + 255) / 256, 256, 0, stream>>>(cnt, N_NODES);
  count_dst<<<(N_EDGES + 255) / 256, 256, 0, stream>>>(edst, N_EDGES, cnt);
  scan_blocks<<<nscan, 256, 0, stream>>>(cnt, row_ptr, bsums, N_NODES);
  scan_bsums<<<1, 64, 0, stream>>>(bsums, nscan);
  add_back<<<(N_NODES + 256) / 256, 256, 0, stream>>>(row_ptr, bsums, wp, N_NODES, Et);
  scatter_edges<<<(Et + 255) / 256, 256, 0, stream>>>(esrc, edst, N_EDGES, N_NODES, wp, csr);

  // ---- conv1 (bf16 MFMA) ----
  gemm_bf16_kernel<<<dim3(gx, HC / 64), 256, 0, stream>>>(
      x_bf, W1T, h_bf, N_NODES, IN_CH, HC);
  al_kernel_bf<<<gagg, 256, 0, stream>>>(h_bf, a_src1, a_dst1, al_s, al_d, N_NODES);
  agg_kernel<false><<<gagg, 256, 0, stream>>>(h_bf, al_s, al_d, row_ptr, csr,
                                              b1, nullptr, f1_bf, N_NODES);

  // ---- conv2 (bf16 MFMA) + residual ----
  gemm_bf16_kernel<<<dim3(gx, HC / 64), 256, 0, stream>>>(
      f1_bf, W2T, h_bf, N_NODES, HC, HC);
  al_kernel_bf<<<gagg, 256, 0, stream>>>(h_bf, a_src2, a_dst2, al_s, al_d, N_NODES);
  gemm_kernel<<<dim3(gx, 1), 256, 0, stream>>>(x, Wfc, bfc, xch, N_NODES, IN_CH, OUT_CC);
  agg_kernel<true><<<gagg, 256, 0, stream>>>(h_bf, al_s, al_d, row_ptr, csr,
                                             b2, xch, out, N_NODES);
}